// Round 9
// baseline (123.463 us; speedup 1.0000x reference)
//
#include <hip/hip_runtime.h>
#include <math.h>

#define BIGV  1.0e8f
#define PLANE (512 * 512)            // 262144
#define NTOT  (8 * PLANE)            // 2097152
#define PROWS 640                    // 64 pad + 512 + 64 pad
#define PSTRIDE (PROWS * 512)        // floats per padded plane

// ---------------------------------------------------------------------------
// Kernel 1: 1-D DT along axis 3 (binary input) via ballot-built 512-bit line
// mask + clz/ffs nearest-set-bit. Writes h^2 (f32, exact) into a PADDED plane
// layout: row i2 lives at (64+i2); rows 0..63 and 576..639 are BIG pads.
// Blocks >= 4096 write the pads; pad thread 0 zeroes the finalize counter.
// ---------------------------------------------------------------------------
__global__ __launch_bounds__(512) void dt_axis3(const int* __restrict__ y,
                                                float* __restrict__ g1p,
                                                unsigned int* __restrict__ counter) {
    int blk = blockIdx.x;
    if (blk >= 4096) {                                 // pad writer: 1024 blocks
        int idx = (blk - 4096) * 512 + threadIdx.x;    // [0, 524288)
        int plane = idx >> 16;
        int rem   = idx & 65535;
        int r     = rem >> 9;                          // 0..127
        int c     = rem & 511;
        int row   = (r < 64) ? r : (r + 512);          // 0..63 or 576..639
        g1p[plane * PSTRIDE + row * 512 + c] = BIGV;
        if (idx == 0) *counter = 0u;
        return;
    }
    __shared__ unsigned long long words[8];
    int i = threadIdx.x;                               // position in line
    int e = blk * 512 + i;                             // y index (lines contiguous)
    unsigned long long bal = __ballot(y[e] != 0);
    int wid  = i >> 6;
    int lane = i & 63;
    if (lane == 0) words[wid] = bal;
    __syncthreads();

    int k = wid, b = lane;
    int dr = 1 << 30;
    {
        unsigned long long m0 = words[k] & (~0ull << b);
        if (m0) {
            dr = (__ffsll((long long)m0) - 1) - b;
        } else {
            #pragma unroll
            for (int k2 = 0; k2 < 8; ++k2) {
                if (k2 > k && dr == (1 << 30) && words[k2]) {
                    dr = (k2 << 6) + (__ffsll((long long)words[k2]) - 1) - i;
                }
            }
        }
    }
    int dl = 1 << 30;
    {
        unsigned long long m0 = words[k] & (~0ull >> (63 - b));
        if (m0) {
            dl = b - (63 - __clzll((long long)m0));
        } else {
            #pragma unroll
            for (int k2 = 7; k2 >= 0; --k2) {
                if (k2 < k && dl == (1 << 30) && words[k2]) {
                    dl = i - ((k2 << 6) + 63 - __clzll((long long)words[k2]));
                }
            }
        }
    }
    int d = min(dl, dr);
    float h2 = (d > 511) ? BIGV : (float)(d * d);      // exact: d*d < 2^24
    int bb = blk >> 9, i2 = blk & 511;
    g1p[bb * PSTRIDE + (64 + i2) * 512 + i] = h2;
}

// ---------------------------------------------------------------------------
// Kernel 2: 1-D squared DT along axis 2. ONE PIXEL PER THREAD (per-pixel
// early exit = minimum iteration count), branchless inner loop over padded
// rows. Lanes vary along contiguous i3 -> coalesced 256B row segments.
// (R7-proven shape — do not fuse, do not batch, do not vectorize.)
// ---------------------------------------------------------------------------
__global__ __launch_bounds__(256) void dt_axis2(const float* __restrict__ g1p,
                                                float* __restrict__ D2) {
    int e = blockIdx.x * 256 + threadIdx.x;            // [0, NTOT)
    int b   = e >> 18;                                 // batch
    int rem = e & (PLANE - 1);
    int i2  = rem >> 9;                                // row
    int i3  = rem & 511;                               // col
    const float* base = g1p + b * PSTRIDE + (64 + i2) * 512 + i3;

    float m = *base;
    const float* up = base;
    const float* dn = base;
    int r = 1;
    for (; r < 64; ++r) {
        float fr2 = (float)(r * r);
        if (fr2 >= m) break;
        up -= 512; dn += 512;
        m = fminf(m, fminf(*up, *dn) + fr2);           // pads are BIG: never win
    }
    if (r == 64) {                                     // ultra-rare exact tail
        for (; r < 512; ++r) {
            float fr2 = (float)(r * r);
            if (fr2 >= m) break;
            int upr = i2 - r, dnr = i2 + r;
            if (upr < 0 && dnr >= 512) break;
            if (upr >= 0)  m = fminf(m, g1p[b * PSTRIDE + (64 + upr) * 512 + i3] + fr2);
            if (dnr < 512) m = fminf(m, g1p[b * PSTRIDE + (64 + dnr) * 512 + i3] + fr2);
        }
    }
    D2[e] = m;                                         // exact integer < 2^24
}

// ---------------------------------------------------------------------------
// Kernel 3: axis-0 (length 8, brute 8x8 min-plus) + sqrt + sigmoid(x)*d +
// deterministic reduction; last-arriving block does the fixed-order final sum.
// ---------------------------------------------------------------------------
__device__ inline double wave_reduce_d(double v) {
    #pragma unroll
    for (int off = 32; off > 0; off >>= 1) v += __shfl_down(v, off, 64);
    return v;
}

__global__ __launch_bounds__(256) void axis0_epilogue(const float* __restrict__ D2,
                                                      const float* __restrict__ x,
                                                      double* __restrict__ partials,
                                                      unsigned int* __restrict__ counter,
                                                      float* __restrict__ out) {
    int s = blockIdx.x * 256 + threadIdx.x;            // spatial [0, PLANE)
    float v[8];
    #pragma unroll
    for (int b = 0; b < 8; ++b) v[b] = D2[b * PLANE + s];

    double acc = 0.0;
    #pragma unroll
    for (int b = 0; b < 8; ++b) {
        float m = BIGV;
        #pragma unroll
        for (int bp = 0; bp < 8; ++bp) {
            float db = (float)((b - bp) * (b - bp));   // compile-time const
            m = fminf(m, v[bp] + db);
        }
        float xv  = x[b * PLANE + s];
        float sig = 1.0f / (1.0f + expf(-xv));
        acc += (double)(sig * sqrtf(m));
    }

    __shared__ double lds[4];
    __shared__ int is_last;
    double w = wave_reduce_d(acc);
    int lane = threadIdx.x & 63;
    int wid  = threadIdx.x >> 6;
    if (lane == 0) lds[wid] = w;
    __syncthreads();
    if (threadIdx.x == 0) {
        double tsum = lds[0] + lds[1] + lds[2] + lds[3];
        __hip_atomic_store(&partials[blockIdx.x], tsum, __ATOMIC_RELEASE,
                           __HIP_MEMORY_SCOPE_AGENT);
        unsigned int done = __hip_atomic_fetch_add(counter, 1u, __ATOMIC_ACQ_REL,
                                                   __HIP_MEMORY_SCOPE_AGENT);
        is_last = (done == gridDim.x - 1) ? 1 : 0;
    }
    __syncthreads();
    if (is_last) {
        double a = 0.0;
        for (int i = threadIdx.x; i < 1024; i += 256)
            a += __hip_atomic_load(&partials[i], __ATOMIC_ACQUIRE,
                                   __HIP_MEMORY_SCOPE_AGENT);
        double ww = wave_reduce_d(a);
        if (lane == 0) lds[wid] = ww;
        __syncthreads();
        if (threadIdx.x == 0)
            out[0] = (float)((lds[0] + lds[1] + lds[2] + lds[3]) / (double)NTOT);
    }
}

// ---------------------------------------------------------------------------
extern "C" void kernel_launch(void* const* d_in, const int* in_sizes, int n_in,
                              void* d_out, int out_size, void* d_ws, size_t ws_size,
                              hipStream_t stream) {
    const float* x = (const float*)d_in[0];
    const int*   y = (const int*)d_in[1];
    float* out = (float*)d_out;

    float*  g1p      = (float*)d_ws;                   // 10.5 MB padded
    float*  D2       = g1p + 8 * PSTRIDE;              // 8 MB
    double* partials = (double*)(D2 + NTOT);           // 8 KB (1024 doubles)
    unsigned int* counter = (unsigned int*)(partials + 1024);

    dt_axis3<<<5120, 512, 0, stream>>>(y, g1p, counter);
    dt_axis2<<<NTOT / 256, 256, 0, stream>>>(g1p, D2);
    axis0_epilogue<<<PLANE / 256, 256, 0, stream>>>(D2, x, partials, counter, out);
}

// Round 10
// 96.574 us; speedup vs baseline: 1.2784x; 1.2784x over previous
//
#include <hip/hip_runtime.h>
#include <math.h>

#define BIGV  1.0e8f
#define PLANE (512 * 512)            // 262144
#define NTOT  (8 * PLANE)            // 2097152
#define PROWS 640                    // 64 pad + 512 + 64 pad
#define PSTRIDE (PROWS * 512)        // floats per padded plane

// ---------------------------------------------------------------------------
// Kernel 1: 1-D DT along axis 3 (binary input) via ballot-built 512-bit line
// mask + clz/ffs nearest-set-bit. Writes h^2 (f32, exact) into a PADDED plane
// layout: row i2 lives at (64+i2); rows 0..63 and 576..639 are BIG pads.
// Blocks >= 4096 write the pads. NO atomics anywhere (device-scope atomics
// cost ~25 us in L2 writeback/invalidate on gfx950 — measured R5/R8/R9).
// ---------------------------------------------------------------------------
__global__ __launch_bounds__(512) void dt_axis3(const int* __restrict__ y,
                                                float* __restrict__ g1p) {
    int blk = blockIdx.x;
    if (blk >= 4096) {                                 // pad writer: 1024 blocks
        int idx = (blk - 4096) * 512 + threadIdx.x;    // [0, 524288)
        int plane = idx >> 16;
        int rem   = idx & 65535;
        int r     = rem >> 9;                          // 0..127
        int c     = rem & 511;
        int row   = (r < 64) ? r : (r + 512);          // 0..63 or 576..639
        g1p[plane * PSTRIDE + row * 512 + c] = BIGV;
        return;
    }
    __shared__ unsigned long long words[8];
    int i = threadIdx.x;                               // position in line
    int e = blk * 512 + i;                             // y index (lines contiguous)
    unsigned long long bal = __ballot(y[e] != 0);
    int wid  = i >> 6;
    int lane = i & 63;
    if (lane == 0) words[wid] = bal;
    __syncthreads();

    int k = wid, b = lane;
    int dr = 1 << 30;
    {
        unsigned long long m0 = words[k] & (~0ull << b);
        if (m0) {
            dr = (__ffsll((long long)m0) - 1) - b;
        } else {
            #pragma unroll
            for (int k2 = 0; k2 < 8; ++k2) {
                if (k2 > k && dr == (1 << 30) && words[k2]) {
                    dr = (k2 << 6) + (__ffsll((long long)words[k2]) - 1) - i;
                }
            }
        }
    }
    int dl = 1 << 30;
    {
        unsigned long long m0 = words[k] & (~0ull >> (63 - b));
        if (m0) {
            dl = b - (63 - __clzll((long long)m0));
        } else {
            #pragma unroll
            for (int k2 = 7; k2 >= 0; --k2) {
                if (k2 < k && dl == (1 << 30) && words[k2]) {
                    dl = i - ((k2 << 6) + 63 - __clzll((long long)words[k2]));
                }
            }
        }
    }
    int d = min(dl, dr);
    float h2 = (d > 511) ? BIGV : (float)(d * d);      // exact: d*d < 2^24
    int bb = blk >> 9, i2 = blk & 511;
    g1p[bb * PSTRIDE + (64 + i2) * 512 + i] = h2;
}

// ---------------------------------------------------------------------------
// Kernel 2: 1-D squared DT along axis 2. ONE PIXEL PER THREAD (R7-proven
// shape), software-pipelined: loads for radius r+1 issue before the break
// check consumes m's update. Break uses the previous m — exiting later is
// always exact. Max prefetch radius = 64 fits the 64-row pad exactly.
// r^2 via exact fp32 recurrence (small ints exact in fp32).
// ---------------------------------------------------------------------------
__global__ __launch_bounds__(256) void dt_axis2(const float* __restrict__ g1p,
                                                float* __restrict__ D2) {
    int e = blockIdx.x * 256 + threadIdx.x;            // [0, NTOT)
    int b   = e >> 18;                                 // batch
    int rem = e & (PLANE - 1);
    int i2  = rem >> 9;                                // row
    int i3  = rem & 511;                               // col
    const float* base = g1p + b * PSTRIDE + (64 + i2) * 512 + i3;

    float m  = *base;
    float au = base[-512];                             // radius-1 candidates
    float ad = base[+512];
    const float* up = base - 512;
    const float* dn = base + 512;
    float fr2 = 1.0f, dstep = 3.0f;                    // r^2: 1,4,9,... exact
    int r = 1;
    for (; r < 64; ++r) {
        if (fr2 >= m) break;                           // uses prev-iter m: safe
        float cand = fminf(au, ad) + fr2;
        au = up[-512]; ad = dn[+512];                  // prefetch radius r+1
        up -= 512; dn += 512;
        m = fminf(m, cand);                            // pads are BIG: never win
        fr2 += dstep; dstep += 2.0f;
    }
    if (r == 64) {                                     // ultra-rare exact tail
        for (; r < 512; ++r) {
            float f2 = (float)(r * r);
            if (f2 >= m) break;
            int upr = i2 - r, dnr = i2 + r;
            if (upr < 0 && dnr >= 512) break;
            if (upr >= 0)  m = fminf(m, g1p[b * PSTRIDE + (64 + upr) * 512 + i3] + f2);
            if (dnr < 512) m = fminf(m, g1p[b * PSTRIDE + (64 + dnr) * 512 + i3] + f2);
        }
    }
    D2[e] = m;                                         // exact integer < 2^24
}

// ---------------------------------------------------------------------------
// Kernel 3: axis-0 (length 8, brute 8x8 min-plus) + sqrt + sigmoid(x)*d +
// deterministic block partial sums (double). NO atomics.
// ---------------------------------------------------------------------------
__device__ inline double wave_reduce_d(double v) {
    #pragma unroll
    for (int off = 32; off > 0; off >>= 1) v += __shfl_down(v, off, 64);
    return v;
}

__global__ __launch_bounds__(256) void axis0_epilogue(const float* __restrict__ D2,
                                                      const float* __restrict__ x,
                                                      double* __restrict__ partials) {
    int s = blockIdx.x * 256 + threadIdx.x;            // spatial [0, PLANE)
    float v[8];
    #pragma unroll
    for (int b = 0; b < 8; ++b) v[b] = D2[b * PLANE + s];

    double acc = 0.0;
    #pragma unroll
    for (int b = 0; b < 8; ++b) {
        float m = BIGV;
        #pragma unroll
        for (int bp = 0; bp < 8; ++bp) {
            float db = (float)((b - bp) * (b - bp));   // compile-time const
            m = fminf(m, v[bp] + db);
        }
        float xv  = x[b * PLANE + s];
        float sig = 1.0f / (1.0f + expf(-xv));
        acc += (double)(sig * sqrtf(m));
    }

    __shared__ double lds[4];
    double w = wave_reduce_d(acc);
    int lane = threadIdx.x & 63;
    int wid  = threadIdx.x >> 6;
    if (lane == 0) lds[wid] = w;
    __syncthreads();
    if (wid == 0) {
        double t = (lane < 4) ? lds[lane] : 0.0;
        #pragma unroll
        for (int off = 2; off > 0; off >>= 1) t += __shfl_down(t, off, 64);
        if (lane == 0) partials[blockIdx.x] = t;
    }
}

__global__ __launch_bounds__(256) void finalize(const double* __restrict__ partials,
                                                float* __restrict__ out) {
    double a = 0.0;
    for (int i = threadIdx.x; i < 1024; i += 256) a += partials[i];
    __shared__ double lds[4];
    double w = wave_reduce_d(a);
    int lane = threadIdx.x & 63;
    int wid  = threadIdx.x >> 6;
    if (lane == 0) lds[wid] = w;
    __syncthreads();
    if (threadIdx.x == 0) {
        double total = lds[0] + lds[1] + lds[2] + lds[3];
        out[0] = (float)(total / (double)NTOT);
    }
}

// ---------------------------------------------------------------------------
extern "C" void kernel_launch(void* const* d_in, const int* in_sizes, int n_in,
                              void* d_out, int out_size, void* d_ws, size_t ws_size,
                              hipStream_t stream) {
    const float* x = (const float*)d_in[0];
    const int*   y = (const int*)d_in[1];
    float* out = (float*)d_out;

    float*  g1p      = (float*)d_ws;                   // 10.5 MB padded
    float*  D2       = g1p + 8 * PSTRIDE;              // 8 MB
    double* partials = (double*)(D2 + NTOT);           // 8 KB (1024 doubles)

    dt_axis3<<<5120, 512, 0, stream>>>(y, g1p);
    dt_axis2<<<NTOT / 256, 256, 0, stream>>>(g1p, D2);
    axis0_epilogue<<<PLANE / 256, 256, 0, stream>>>(D2, x, partials);
    finalize<<<1, 256, 0, stream>>>(partials, out);
}